// Round 1
// baseline (2915.187 us; speedup 1.0000x reference)
//
#include <hip/hip_runtime.h>

#define NN 16384
#define NE 400000
#define H 128
#define H3 384
#define RD 20
#define TILE_E 64

__device__ __forceinline__ float silu_f(float x) {
  return x / (1.0f + __expf(-x));
}

// ---------------------------------------------------------------------------
// t = silu(s @ sW1 + sb1) @ sW2 + sb2   (per-node; gathered per-edge later)
// 16 nodes per block, 256 threads. c = tid&127 (output col), half = tid>>7.
// ---------------------------------------------------------------------------
__global__ __launch_bounds__(256) void node_mlp_kernel(
    const float* __restrict__ s, const float* __restrict__ sW1,
    const float* __restrict__ sb1, const float* __restrict__ sW2,
    const float* __restrict__ sb2, float* __restrict__ t)
{
  __shared__ float s_l[16 * H];   // 8 KB
  __shared__ float h1_l[16 * H];  // 8 KB
  const int tid  = threadIdx.x;
  const int c    = tid & (H - 1);
  const int half = tid >> 7;  // 0..1 -> nodes half*8 .. half*8+8
  const int n0   = blockIdx.x * 16;

  {  // load 16x128 s tile (2048 floats)
    const float4* sg = (const float4*)(s + (size_t)n0 * H);
    float4* sl = (float4*)s_l;
    sl[tid]       = sg[tid];
    sl[tid + 256] = sg[tid + 256];
  }
  __syncthreads();

  // GEMM1: h1 = silu(s @ sW1 + sb1)
  float a1[8];
  {
    const float b = sb1[c];
#pragma unroll
    for (int n = 0; n < 8; ++n) a1[n] = b;
  }
  for (int k = 0; k < H; ++k) {
    const float w = sW1[k * H + c];
#pragma unroll
    for (int n = 0; n < 8; ++n)
      a1[n] = fmaf(s_l[(half * 8 + n) * H + k], w, a1[n]);
  }
#pragma unroll
  for (int n = 0; n < 8; ++n)
    h1_l[(half * 8 + n) * H + c] = silu_f(a1[n]);
  __syncthreads();

  // GEMM2: t = h1 @ sW2 + sb2  (each thread: 8 nodes x cols {c, c+128, c+256})
  float a2[8][3];
  {
    const float b0 = sb2[c], b1 = sb2[H + c], b2 = sb2[2 * H + c];
#pragma unroll
    for (int n = 0; n < 8; ++n) { a2[n][0] = b0; a2[n][1] = b1; a2[n][2] = b2; }
  }
  for (int k = 0; k < H; ++k) {
    const float w0 = sW2[k * H3 + c];
    const float w1 = sW2[k * H3 + H + c];
    const float w2 = sW2[k * H3 + 2 * H + c];
#pragma unroll
    for (int n = 0; n < 8; ++n) {
      const float h = h1_l[(half * 8 + n) * H + k];
      a2[n][0] = fmaf(h, w0, a2[n][0]);
      a2[n][1] = fmaf(h, w1, a2[n][1]);
      a2[n][2] = fmaf(h, w2, a2[n][2]);
    }
  }
#pragma unroll
  for (int n = 0; n < 8; ++n) {
    float* tr = t + (size_t)(n0 + half * 8 + n) * H3;
    tr[c]         = a2[n][0];
    tr[H + c]     = a2[n][1];
    tr[2 * H + c] = a2[n][2];
  }
}

// ---------------------------------------------------------------------------
// Fused edge kernel: 64 edges/block, 256 threads.
//   h   = silu(rbf @ fW1 + fb1)              [64 x 128]  (LDS)
//   msg = (h @ fW2 + fb2) * t[src]           [64 x 384]  (registers)
//   atomicAdd ds -> out_s[dst], dv -> out_v[dst]
// Thread (ty=tid>>5, tx=tid&31): edges ty*8..+8, cols {c0..c0+4}+{0,128,256}
// with c0 = tx*4  (so ds/dv_vec/dv_rad for one col live in the same thread).
// ---------------------------------------------------------------------------
__global__ __launch_bounds__(256, 2) void edge_kernel(
    const int* __restrict__ ei, const float* __restrict__ rbf,
    const float* __restrict__ unit, const float* __restrict__ fW1,
    const float* __restrict__ fb1, const float* __restrict__ fW2,
    const float* __restrict__ fb2, const float* __restrict__ t,
    const float* __restrict__ v, float* __restrict__ out_s,
    float* __restrict__ out_v)
{
  __shared__ float h_l[TILE_E * H];     // 32 KB
  __shared__ float w_l[8 * H3];         // 12 KB (fW2 K-chunk)
  __shared__ float rbf_l[TILE_E * 24];  // 6 KB (stride 24: 16B-aligned rows)
  __shared__ float fW1_l[RD * H];       // 10 KB
  __shared__ int   src_l[TILE_E];
  __shared__ int   dst_l[TILE_E];
  __shared__ float unit_l[TILE_E * 3];

  const int tid = threadIdx.x;
  const int e0  = blockIdx.x * TILE_E;

  // ---- stage 0: tile loads ----
  {  // rbf tile: 64*20 = 1280 floats = 320 float4 (4 divides 20: no row split)
    const float4* rg = (const float4*)(rbf + (size_t)e0 * RD);
    {
      const float4 rv = rg[tid % 320];  // tid 0..255 all valid
      if (tid < 320) {
        const int g = tid * 4;
        *(float4*)&rbf_l[(g / RD) * 24 + (g % RD)] = rv;
      }
      const int idx = tid + 256;
      if (idx < 320) {
        const float4 rv2 = rg[idx];
        const int g = idx * 4;
        *(float4*)&rbf_l[(g / RD) * 24 + (g % RD)] = rv2;
      }
    }
  }
  {  // fW1: 2560 floats = 640 float4
    const float4* f4 = (const float4*)fW1;
    float4* l4 = (float4*)fW1_l;
    l4[tid]       = f4[tid];
    l4[tid + 256] = f4[tid + 256];
    if (tid < 128) l4[tid + 512] = f4[tid + 512];
  }
  if (tid < TILE_E) {
    src_l[tid] = ei[e0 + tid];
    dst_l[tid] = ei[NE + e0 + tid];
  }
  if (tid < TILE_E * 3) unit_l[tid] = unit[(size_t)e0 * 3 + tid];
  __syncthreads();

  // ---- stage 1: h = silu(rbf @ fW1 + fb1) ----
  {
    const int c  = tid & (H - 1);
    const int eh = tid >> 7;  // 0..1: edges eh*32 .. eh*32+32
    float wf[RD];
#pragma unroll
    for (int k = 0; k < RD; ++k) wf[k] = fW1_l[k * H + c];
    const float b = fb1[c];
    for (int i = 0; i < 32; ++i) {
      const int e = eh * 32 + i;
      float x = b;
#pragma unroll
      for (int k = 0; k < RD; ++k)
        x = fmaf(rbf_l[e * 24 + k], wf[k], x);
      h_l[e * H + c] = silu_f(x);
    }
  }
  __syncthreads();

  // ---- stage 2: GEMM  msg_pre = h @ fW2  (per-thread 8 edges x 12 cols) ----
  const int tx = tid & 31;
  const int ty = tid >> 5;
  const int c0 = tx * 4;

  float acc[8][12];
#pragma unroll
  for (int i = 0; i < 8; ++i)
#pragma unroll
    for (int j = 0; j < 12; ++j) acc[i][j] = 0.0f;

  for (int kc = 0; kc < 16; ++kc) {  // 16 chunks of K=8
    {  // stage fW2 rows kc*8..+8 into LDS: 3072 floats = 768 float4
      const float4* wg = (const float4*)(fW2 + (size_t)kc * 8 * H3);
      float4* wl = (float4*)w_l;
#pragma unroll
      for (int r = 0; r < 3; ++r) wl[tid + r * 256] = wg[tid + r * 256];
    }
    __syncthreads();
#pragma unroll
    for (int k4 = 0; k4 < 2; ++k4) {  // two groups of 4 k's
      float4 hreg[8];
#pragma unroll
      for (int i = 0; i < 8; ++i)
        hreg[i] = *(const float4*)&h_l[(ty * 8 + i) * H + kc * 8 + k4 * 4];
#pragma unroll
      for (int dk = 0; dk < 4; ++dk) {
        const int kk = k4 * 4 + dk;
        const float4 w0 = *(const float4*)&w_l[kk * H3 + c0];
        const float4 w1 = *(const float4*)&w_l[kk * H3 + H + c0];
        const float4 w2 = *(const float4*)&w_l[kk * H3 + 2 * H + c0];
#pragma unroll
        for (int i = 0; i < 8; ++i) {
          const float h = ((const float*)&hreg[i])[dk];
          acc[i][0] = fmaf(h, w0.x, acc[i][0]);
          acc[i][1] = fmaf(h, w0.y, acc[i][1]);
          acc[i][2] = fmaf(h, w0.z, acc[i][2]);
          acc[i][3] = fmaf(h, w0.w, acc[i][3]);
          acc[i][4] = fmaf(h, w1.x, acc[i][4]);
          acc[i][5] = fmaf(h, w1.y, acc[i][5]);
          acc[i][6] = fmaf(h, w1.z, acc[i][6]);
          acc[i][7] = fmaf(h, w1.w, acc[i][7]);
          acc[i][8]  = fmaf(h, w2.x, acc[i][8]);
          acc[i][9]  = fmaf(h, w2.y, acc[i][9]);
          acc[i][10] = fmaf(h, w2.z, acc[i][10]);
          acc[i][11] = fmaf(h, w2.w, acc[i][11]);
        }
      }
    }
    __syncthreads();
  }

  // ---- stage 3: epilogue — msg = (acc+fb2)*t[src]; scatter-add ----
  float bb[12];
  *(float4*)&bb[0] = *(const float4*)&fb2[c0];
  *(float4*)&bb[4] = *(const float4*)&fb2[H + c0];
  *(float4*)&bb[8] = *(const float4*)&fb2[2 * H + c0];

#pragma unroll
  for (int i = 0; i < 8; ++i) {
    const int e   = ty * 8 + i;
    const int src = src_l[e];
    const int dst = dst_l[e];
    const float* trow = t + (size_t)src * H3;
    const float* vrow = v + (size_t)src * H3;
    float tt[12];
    *(float4*)&tt[0] = *(const float4*)&trow[c0];
    *(float4*)&tt[4] = *(const float4*)&trow[H + c0];
    *(float4*)&tt[8] = *(const float4*)&trow[2 * H + c0];

    float ms[4], mv[4], mr[4];
#pragma unroll
    for (int j = 0; j < 4; ++j) {
      ms[j] = (acc[i][j]     + bb[j])     * tt[j];
      mv[j] = (acc[i][4 + j] + bb[4 + j]) * tt[4 + j];
      mr[j] = (acc[i][8 + j] + bb[8 + j]) * tt[8 + j];
    }
    float* os = out_s + (size_t)dst * H + c0;
#pragma unroll
    for (int j = 0; j < 4; ++j) atomicAdd(&os[j], ms[j]);

    const float u0 = unit_l[e * 3 + 0];
    const float u1 = unit_l[e * 3 + 1];
    const float u2 = unit_l[e * 3 + 2];
    float* ov = out_v + (size_t)dst * H3;
#pragma unroll
    for (int d = 0; d < 3; ++d) {
      const float ud = (d == 0) ? u0 : ((d == 1) ? u1 : u2);
      float vv[4];
      *(float4*)&vv[0] = *(const float4*)&vrow[d * H + c0];
#pragma unroll
      for (int j = 0; j < 4; ++j)
        atomicAdd(&ov[d * H + c0 + j], fmaf(mv[j], vv[j], mr[j] * ud));
    }
  }
}

extern "C" void kernel_launch(void* const* d_in, const int* in_sizes, int n_in,
                              void* d_out, int out_size, void* d_ws, size_t ws_size,
                              hipStream_t stream) {
  const float* s    = (const float*)d_in[0];
  const float* v    = (const float*)d_in[1];
  const int*   ei   = (const int*)d_in[2];
  const float* rbf  = (const float*)d_in[3];
  const float* unit = (const float*)d_in[4];
  const float* fW1  = (const float*)d_in[5];
  const float* fb1  = (const float*)d_in[6];
  const float* fW2  = (const float*)d_in[7];
  const float* fb2  = (const float*)d_in[8];
  const float* sW1  = (const float*)d_in[9];
  const float* sb1  = (const float*)d_in[10];
  const float* sW2  = (const float*)d_in[11];
  const float* sb2  = (const float*)d_in[12];

  float* out_s = (float*)d_out;
  float* out_v = out_s + (size_t)NN * H;
  float* t     = (float*)d_ws;  // [NN, 384] fp32 = 25.2 MB

  // out = (s, v) then accumulate message aggregation atomically
  hipMemcpyAsync(out_s, s, (size_t)NN * H * sizeof(float),
                 hipMemcpyDeviceToDevice, stream);
  hipMemcpyAsync(out_v, v, (size_t)NN * 3 * H * sizeof(float),
                 hipMemcpyDeviceToDevice, stream);

  node_mlp_kernel<<<NN / 16, 256, 0, stream>>>(s, sW1, sb1, sW2, sb2, t);
  edge_kernel<<<NE / TILE_E, 256, 0, stream>>>(ei, rbf, unit, fW1, fb1, fW2,
                                               fb2, t, v, out_s, out_v);
}

// Round 2
// 911.048 us; speedup vs baseline: 3.1998x; 3.1998x over previous
//
#include <hip/hip_runtime.h>

#define NN 16384
#define NE 400000
#define H 128
#define H3 384
#define RD 20
#define TILE_E 64

__device__ __forceinline__ float silu_f(float x) {
  return x / (1.0f + __expf(-x));
}

// ---------------------------------------------------------------------------
// Counting sort of edges by dst: histogram -> scan -> scatter perm
// ---------------------------------------------------------------------------
__global__ __launch_bounds__(256) void hist_kernel(
    const int* __restrict__ ei, int* __restrict__ cnt)
{
  const int e = blockIdx.x * 256 + threadIdx.x;
  if (e < NE) atomicAdd(&cnt[ei[NE + e]], 1);
}

// single block, 256 threads, 64 elements each (NN = 16384)
__global__ __launch_bounds__(256) void scan_kernel(
    const int* __restrict__ cnt, int* __restrict__ off)
{
  __shared__ int part[256];
  const int tid = threadIdx.x;
  const int base = tid * 64;
  int sum = 0;
#pragma unroll
  for (int j = 0; j < 64; ++j) sum += cnt[base + j];
  part[tid] = sum;
  __syncthreads();
  // inclusive Hillis-Steele scan over 256 partials
  for (int d = 1; d < 256; d <<= 1) {
    int y = (tid >= d) ? part[tid - d] : 0;
    __syncthreads();
    part[tid] += y;
    __syncthreads();
  }
  int run = part[tid] - sum;  // exclusive prefix for this thread's chunk
  for (int j = 0; j < 64; ++j) {
    off[base + j] = run;
    run += cnt[base + j];
  }
}

__global__ __launch_bounds__(256) void scatter_kernel(
    const int* __restrict__ ei, int* __restrict__ off, int* __restrict__ perm)
{
  const int e = blockIdx.x * 256 + threadIdx.x;
  if (e < NE) {
    const int pos = atomicAdd(&off[ei[NE + e]], 1);
    perm[pos] = e;
  }
}

// ---------------------------------------------------------------------------
// t = silu(s @ sW1 + sb1) @ sW2 + sb2   (per-node; gathered per-edge later)
// ---------------------------------------------------------------------------
__global__ __launch_bounds__(256) void node_mlp_kernel(
    const float* __restrict__ s, const float* __restrict__ sW1,
    const float* __restrict__ sb1, const float* __restrict__ sW2,
    const float* __restrict__ sb2, float* __restrict__ t)
{
  __shared__ float s_l[16 * H];
  __shared__ float h1_l[16 * H];
  const int tid  = threadIdx.x;
  const int c    = tid & (H - 1);
  const int half = tid >> 7;
  const int n0   = blockIdx.x * 16;

  {
    const float4* sg = (const float4*)(s + (size_t)n0 * H);
    float4* sl = (float4*)s_l;
    sl[tid]       = sg[tid];
    sl[tid + 256] = sg[tid + 256];
  }
  __syncthreads();

  float a1[8];
  {
    const float b = sb1[c];
#pragma unroll
    for (int n = 0; n < 8; ++n) a1[n] = b;
  }
  for (int k = 0; k < H; ++k) {
    const float w = sW1[k * H + c];
#pragma unroll
    for (int n = 0; n < 8; ++n)
      a1[n] = fmaf(s_l[(half * 8 + n) * H + k], w, a1[n]);
  }
#pragma unroll
  for (int n = 0; n < 8; ++n)
    h1_l[(half * 8 + n) * H + c] = silu_f(a1[n]);
  __syncthreads();

  float a2[8][3];
  {
    const float b0 = sb2[c], b1 = sb2[H + c], b2 = sb2[2 * H + c];
#pragma unroll
    for (int n = 0; n < 8; ++n) { a2[n][0] = b0; a2[n][1] = b1; a2[n][2] = b2; }
  }
  for (int k = 0; k < H; ++k) {
    const float w0 = sW2[k * H3 + c];
    const float w1 = sW2[k * H3 + H + c];
    const float w2 = sW2[k * H3 + 2 * H + c];
#pragma unroll
    for (int n = 0; n < 8; ++n) {
      const float h = h1_l[(half * 8 + n) * H + k];
      a2[n][0] = fmaf(h, w0, a2[n][0]);
      a2[n][1] = fmaf(h, w1, a2[n][1]);
      a2[n][2] = fmaf(h, w2, a2[n][2]);
    }
  }
#pragma unroll
  for (int n = 0; n < 8; ++n) {
    float* tr = t + (size_t)(n0 + half * 8 + n) * H3;
    tr[c]         = a2[n][0];
    tr[H + c]     = a2[n][1];
    tr[2 * H + c] = a2[n][2];
  }
}

// ---------------------------------------------------------------------------
// Fused edge kernel over dst-sorted edges (via perm). Epilogue run-reduces
// consecutive same-dst edges in registers; flushes atomics only at dst
// boundaries (expected ~1.29 flushes per 8-edge run vs 8 unsorted).
// ---------------------------------------------------------------------------
__global__ __launch_bounds__(256, 2) void edge_kernel(
    const int* __restrict__ ei, const float* __restrict__ rbf,
    const float* __restrict__ unit, const float* __restrict__ fW1,
    const float* __restrict__ fb1, const float* __restrict__ fW2,
    const float* __restrict__ fb2, const float* __restrict__ t,
    const float* __restrict__ v, const int* __restrict__ perm,
    float* __restrict__ out_s, float* __restrict__ out_v)
{
  __shared__ float h_l[TILE_E * H];     // 32 KB
  __shared__ float w_l[8 * H3];         // 12 KB
  __shared__ float rbf_l[TILE_E * 24];  // 6 KB
  __shared__ float fW1_l[RD * H];       // 10 KB
  __shared__ int   perm_l[TILE_E];
  __shared__ int   src_l[TILE_E];
  __shared__ int   dst_l[TILE_E];
  __shared__ float unit_l[TILE_E * 3];

  const int tid = threadIdx.x;
  const int e0  = blockIdx.x * TILE_E;

  // ---- stage 0a: perm + fW1 (independent of perm) ----
  if (tid < TILE_E) perm_l[tid] = perm[e0 + tid];
  {
    const float4* f4 = (const float4*)fW1;
    float4* l4 = (float4*)fW1_l;
    l4[tid]       = f4[tid];
    l4[tid + 256] = f4[tid + 256];
    if (tid < 128) l4[tid + 512] = f4[tid + 512];
  }
  __syncthreads();

  // ---- stage 0b: gathered per-edge loads through perm ----
  {  // rbf: 64 rows x 20 floats = 5 float4/row (row base 80B: 16B aligned)
    {
      if (tid < 320) {
        const int e = tid / 5, c4 = tid % 5;
        *(float4*)&rbf_l[e * 24 + c4 * 4] =
            *(const float4*)&rbf[(size_t)perm_l[e] * RD + c4 * 4];
      }
      const int idx = tid + 256;
      if (idx < 320) {
        const int e = idx / 5, c4 = idx % 5;
        *(float4*)&rbf_l[e * 24 + c4 * 4] =
            *(const float4*)&rbf[(size_t)perm_l[e] * RD + c4 * 4];
      }
    }
  }
  if (tid < TILE_E) {
    const int pe = perm_l[tid];
    src_l[tid] = ei[pe];
    dst_l[tid] = ei[NE + pe];
  }
  if (tid < TILE_E * 3) {
    const int e = tid / 3, d = tid % 3;
    unit_l[tid] = unit[(size_t)perm_l[e] * 3 + d];
  }
  __syncthreads();

  // ---- stage 1: h = silu(rbf @ fW1 + fb1) ----
  {
    const int c  = tid & (H - 1);
    const int eh = tid >> 7;
    float wf[RD];
#pragma unroll
    for (int k = 0; k < RD; ++k) wf[k] = fW1_l[k * H + c];
    const float b = fb1[c];
    for (int i = 0; i < 32; ++i) {
      const int e = eh * 32 + i;
      float x = b;
#pragma unroll
      for (int k = 0; k < RD; ++k)
        x = fmaf(rbf_l[e * 24 + k], wf[k], x);
      h_l[e * H + c] = silu_f(x);
    }
  }
  __syncthreads();

  // ---- stage 2: GEMM  msg_pre = h @ fW2 ----
  const int tx = tid & 31;
  const int ty = tid >> 5;
  const int c0 = tx * 4;

  float acc[8][12];
#pragma unroll
  for (int i = 0; i < 8; ++i)
#pragma unroll
    for (int j = 0; j < 12; ++j) acc[i][j] = 0.0f;

  for (int kc = 0; kc < 16; ++kc) {
    {
      const float4* wg = (const float4*)(fW2 + (size_t)kc * 8 * H3);
      float4* wl = (float4*)w_l;
#pragma unroll
      for (int r = 0; r < 3; ++r) wl[tid + r * 256] = wg[tid + r * 256];
    }
    __syncthreads();
#pragma unroll
    for (int k4 = 0; k4 < 2; ++k4) {
      float4 hreg[8];
#pragma unroll
      for (int i = 0; i < 8; ++i)
        hreg[i] = *(const float4*)&h_l[(ty * 8 + i) * H + kc * 8 + k4 * 4];
#pragma unroll
      for (int dk = 0; dk < 4; ++dk) {
        const int kk = k4 * 4 + dk;
        const float4 w0 = *(const float4*)&w_l[kk * H3 + c0];
        const float4 w1 = *(const float4*)&w_l[kk * H3 + H + c0];
        const float4 w2 = *(const float4*)&w_l[kk * H3 + 2 * H + c0];
#pragma unroll
        for (int i = 0; i < 8; ++i) {
          const float h = ((const float*)&hreg[i])[dk];
          acc[i][0] = fmaf(h, w0.x, acc[i][0]);
          acc[i][1] = fmaf(h, w0.y, acc[i][1]);
          acc[i][2] = fmaf(h, w0.z, acc[i][2]);
          acc[i][3] = fmaf(h, w0.w, acc[i][3]);
          acc[i][4] = fmaf(h, w1.x, acc[i][4]);
          acc[i][5] = fmaf(h, w1.y, acc[i][5]);
          acc[i][6] = fmaf(h, w1.z, acc[i][6]);
          acc[i][7] = fmaf(h, w1.w, acc[i][7]);
          acc[i][8]  = fmaf(h, w2.x, acc[i][8]);
          acc[i][9]  = fmaf(h, w2.y, acc[i][9]);
          acc[i][10] = fmaf(h, w2.z, acc[i][10]);
          acc[i][11] = fmaf(h, w2.w, acc[i][11]);
        }
      }
    }
    __syncthreads();
  }

  // ---- stage 3: epilogue with run-length reduction over sorted dst ----
  float bb[12];
  *(float4*)&bb[0] = *(const float4*)&fb2[c0];
  *(float4*)&bb[4] = *(const float4*)&fb2[H + c0];
  *(float4*)&bb[8] = *(const float4*)&fb2[2 * H + c0];

  int cur = dst_l[ty * 8];
  float rs[4]  = {0.f, 0.f, 0.f, 0.f};
  float rv[12] = {0.f, 0.f, 0.f, 0.f, 0.f, 0.f, 0.f, 0.f, 0.f, 0.f, 0.f, 0.f};

#pragma unroll
  for (int i = 0; i < 8; ++i) {
    const int e   = ty * 8 + i;
    const int src = src_l[e];
    const float* trow = t + (size_t)src * H3;
    const float* vrow = v + (size_t)src * H3;
    float tt[12];
    *(float4*)&tt[0] = *(const float4*)&trow[c0];
    *(float4*)&tt[4] = *(const float4*)&trow[H + c0];
    *(float4*)&tt[8] = *(const float4*)&trow[2 * H + c0];

    float mv[4], mr[4];
#pragma unroll
    for (int j = 0; j < 4; ++j) {
      rs[j] += (acc[i][j] + bb[j]) * tt[j];
      mv[j]  = (acc[i][4 + j] + bb[4 + j]) * tt[4 + j];
      mr[j]  = (acc[i][8 + j] + bb[8 + j]) * tt[8 + j];
    }
    const float u0 = unit_l[e * 3 + 0];
    const float u1 = unit_l[e * 3 + 1];
    const float u2 = unit_l[e * 3 + 2];
#pragma unroll
    for (int d = 0; d < 3; ++d) {
      const float ud = (d == 0) ? u0 : ((d == 1) ? u1 : u2);
      float vv[4];
      *(float4*)&vv[0] = *(const float4*)&vrow[d * H + c0];
#pragma unroll
      for (int j = 0; j < 4; ++j)
        rv[d * 4 + j] = fmaf(mv[j], vv[j], fmaf(mr[j], ud, rv[d * 4 + j]));
    }

    const int nxt = (i < 7) ? dst_l[e + 1] : -1;
    if (nxt != cur) {  // flush run
      float* os = out_s + (size_t)cur * H + c0;
#pragma unroll
      for (int j = 0; j < 4; ++j) atomicAdd(&os[j], rs[j]);
      float* ov = out_v + (size_t)cur * H3;
#pragma unroll
      for (int d = 0; d < 3; ++d)
#pragma unroll
        for (int j = 0; j < 4; ++j)
          atomicAdd(&ov[d * H + c0 + j], rv[d * 4 + j]);
#pragma unroll
      for (int j = 0; j < 4; ++j) rs[j] = 0.f;
#pragma unroll
      for (int j = 0; j < 12; ++j) rv[j] = 0.f;
      cur = nxt;
    }
  }
}

extern "C" void kernel_launch(void* const* d_in, const int* in_sizes, int n_in,
                              void* d_out, int out_size, void* d_ws, size_t ws_size,
                              hipStream_t stream) {
  const float* s    = (const float*)d_in[0];
  const float* v    = (const float*)d_in[1];
  const int*   ei   = (const int*)d_in[2];
  const float* rbf  = (const float*)d_in[3];
  const float* unit = (const float*)d_in[4];
  const float* fW1  = (const float*)d_in[5];
  const float* fb1  = (const float*)d_in[6];
  const float* fW2  = (const float*)d_in[7];
  const float* fb2  = (const float*)d_in[8];
  const float* sW1  = (const float*)d_in[9];
  const float* sb1  = (const float*)d_in[10];
  const float* sW2  = (const float*)d_in[11];
  const float* sb2  = (const float*)d_in[12];

  float* out_s = (float*)d_out;
  float* out_v = out_s + (size_t)NN * H;

  // workspace layout
  float* t   = (float*)d_ws;                    // NN*384 floats = 25.2 MB
  int*  cnt  = (int*)(t + (size_t)NN * H3);     // NN ints
  int*  off  = cnt + NN;                        // NN ints
  int*  perm = off + NN;                        // NE ints

  hipMemcpyAsync(out_s, s, (size_t)NN * H * sizeof(float),
                 hipMemcpyDeviceToDevice, stream);
  hipMemcpyAsync(out_v, v, (size_t)NN * 3 * H * sizeof(float),
                 hipMemcpyDeviceToDevice, stream);
  hipMemsetAsync(cnt, 0, NN * sizeof(int), stream);

  hist_kernel<<<(NE + 255) / 256, 256, 0, stream>>>(ei, cnt);
  scan_kernel<<<1, 256, 0, stream>>>(cnt, off);
  scatter_kernel<<<(NE + 255) / 256, 256, 0, stream>>>(ei, off, perm);

  node_mlp_kernel<<<NN / 16, 256, 0, stream>>>(s, sW1, sb1, sW2, sb2, t);
  edge_kernel<<<NE / TILE_E, 256, 0, stream>>>(ei, rbf, unit, fW1, fb1, fW2,
                                               fb2, t, v, perm, out_s, out_v);
}